// Round 1
// baseline (34.568 us; speedup 1.0000x reference)
//
#include <hip/hip_runtime.h>

// Householder reflection: out = z - 2 * v * (v.z) / (v.v), row-wise.
// B = 16384 rows, L = 1024 cols, fp32.
//
// One 64-lane wave per row. Each lane holds 4x float4 of v and z
// (64 lanes * 16 floats = 1024 = L), so the row stays in registers:
// single read of v and z, single write of out -> minimal HBM traffic.

constexpr int L = 1024;
constexpr int F4_PER_ROW = L / 4;        // 256 float4 per row
constexpr int WAVES_PER_BLOCK = 4;
constexpr int THREADS = WAVES_PER_BLOCK * 64;

__global__ __launch_bounds__(THREADS) void householder_kernel(
    const float4* __restrict__ v4, const float4* __restrict__ z4,
    float4* __restrict__ o4, int B) {
  const int wave = threadIdx.x >> 6;
  const int lane = threadIdx.x & 63;
  const int row = blockIdx.x * WAVES_PER_BLOCK + wave;
  if (row >= B) return;

  const float4* __restrict__ vr = v4 + (size_t)row * F4_PER_ROW;
  const float4* __restrict__ zr = z4 + (size_t)row * F4_PER_ROW;

  float4 va[4], za[4];
  float vz = 0.0f, vv = 0.0f;
#pragma unroll
  for (int k = 0; k < 4; ++k) {
    va[k] = vr[k * 64 + lane];
    za[k] = zr[k * 64 + lane];
    vz += va[k].x * za[k].x + va[k].y * za[k].y +
          va[k].z * za[k].z + va[k].w * za[k].w;
    vv += va[k].x * va[k].x + va[k].y * va[k].y +
          va[k].z * va[k].z + va[k].w * va[k].w;
  }

  // Wave-wide butterfly reduction over 64 lanes (wave = 64 on CDNA).
#pragma unroll
  for (int off = 32; off >= 1; off >>= 1) {
    vz += __shfl_xor(vz, off, 64);
    vv += __shfl_xor(vv, off, 64);
  }

  const float s = -2.0f * vz / vv;

  float4* __restrict__ orow = o4 + (size_t)row * F4_PER_ROW;
#pragma unroll
  for (int k = 0; k < 4; ++k) {
    float4 o;
    o.x = fmaf(s, va[k].x, za[k].x);
    o.y = fmaf(s, va[k].y, za[k].y);
    o.z = fmaf(s, va[k].z, za[k].z);
    o.w = fmaf(s, va[k].w, za[k].w);
    orow[k * 64 + lane] = o;
  }
}

extern "C" void kernel_launch(void* const* d_in, const int* in_sizes, int n_in,
                              void* d_out, int out_size, void* d_ws, size_t ws_size,
                              hipStream_t stream) {
  const float4* v = (const float4*)d_in[0];
  const float4* z = (const float4*)d_in[1];
  float4* out = (float4*)d_out;
  const int B = in_sizes[0] / L;  // 16384
  const int grid = (B + WAVES_PER_BLOCK - 1) / WAVES_PER_BLOCK;
  householder_kernel<<<grid, THREADS, 0, stream>>>(v, z, out, B);
}

// Round 2
// 33.889 us; speedup vs baseline: 1.0200x; 1.0200x over previous
//
#include <hip/hip_runtime.h>

// Householder reflection: out = z - 2 * v * (v.z) / (v.v), row-wise.
// B = 16384 rows, L = 1024 cols, fp32.
//
// One 64-lane wave per row; row lives in registers (4x float4 of v and z
// per lane). Output stores are NON-TEMPORAL so they bypass/no-allocate in
// L2/L3 -> the 128 MiB of inputs stays Infinity-Cache-resident across graph
// replays, and HBM traffic drops to the 64 MiB output write stream.

typedef float fvec4 __attribute__((ext_vector_type(4)));

constexpr int L = 1024;
constexpr int F4_PER_ROW = L / 4;        // 256 float4 per row
constexpr int WAVES_PER_BLOCK = 4;
constexpr int THREADS = WAVES_PER_BLOCK * 64;

__global__ __launch_bounds__(THREADS) void householder_kernel(
    const fvec4* __restrict__ v4, const fvec4* __restrict__ z4,
    fvec4* __restrict__ o4, int B) {
  const int wave = threadIdx.x >> 6;
  const int lane = threadIdx.x & 63;
  const int row = blockIdx.x * WAVES_PER_BLOCK + wave;
  if (row >= B) return;

  const fvec4* __restrict__ vr = v4 + (size_t)row * F4_PER_ROW;
  const fvec4* __restrict__ zr = z4 + (size_t)row * F4_PER_ROW;

  fvec4 va[4], za[4];
  float vz = 0.0f, vv = 0.0f;
#pragma unroll
  for (int k = 0; k < 4; ++k) {
    va[k] = vr[k * 64 + lane];
    za[k] = zr[k * 64 + lane];
  }
#pragma unroll
  for (int k = 0; k < 4; ++k) {
    vz += va[k].x * za[k].x + va[k].y * za[k].y +
          va[k].z * za[k].z + va[k].w * za[k].w;
    vv += va[k].x * va[k].x + va[k].y * va[k].y +
          va[k].z * va[k].z + va[k].w * va[k].w;
  }

  // Wave-wide butterfly reduction over 64 lanes.
#pragma unroll
  for (int off = 32; off >= 1; off >>= 1) {
    vz += __shfl_xor(vz, off, 64);
    vv += __shfl_xor(vv, off, 64);
  }

  const float s = -2.0f * vz / vv;

  fvec4* __restrict__ orow = o4 + (size_t)row * F4_PER_ROW;
#pragma unroll
  for (int k = 0; k < 4; ++k) {
    fvec4 o;
    o.x = fmaf(s, va[k].x, za[k].x);
    o.y = fmaf(s, va[k].y, za[k].y);
    o.z = fmaf(s, va[k].z, za[k].z);
    o.w = fmaf(s, va[k].w, za[k].w);
    __builtin_nontemporal_store(o, &orow[k * 64 + lane]);
  }
}

extern "C" void kernel_launch(void* const* d_in, const int* in_sizes, int n_in,
                              void* d_out, int out_size, void* d_ws, size_t ws_size,
                              hipStream_t stream) {
  const fvec4* v = (const fvec4*)d_in[0];
  const fvec4* z = (const fvec4*)d_in[1];
  fvec4* out = (fvec4*)d_out;
  const int B = in_sizes[0] / L;  // 16384
  const int grid = (B + WAVES_PER_BLOCK - 1) / WAVES_PER_BLOCK;
  householder_kernel<<<grid, THREADS, 0, stream>>>(v, z, out, B);
}